// Round 11
// baseline (397.968 us; speedup 1.0000x reference)
//
#include <hip/hip_runtime.h>
#include <stdint.h>

#define BB 8192
#define NN 50

typedef _Float16 half8 __attribute__((ext_vector_type(8)));
typedef float floatx4 __attribute__((ext_vector_type(4)));

union FragU { uint4 u; half8 h; };
static __device__ __forceinline__ half8 u2h(uint4 u) { FragU f; f.u = u; return f.h; }

static __device__ __forceinline__ uint32_t pk2u(float a, float b) {
    auto p = __builtin_amdgcn_cvt_pkrtz(a, b);
    uint32_t u; __builtin_memcpy(&u, &p, 4); return u;
}

#define MFMA(A, B, C) __builtin_amdgcn_mfma_f32_16x16x32_f16((A), (B), (C), 0, 0, 0)

static __device__ __forceinline__ float frcp(float x) {
#if __has_builtin(__builtin_amdgcn_rcpf)
    return __builtin_amdgcn_rcpf(x);
#else
    return 1.0f / x;
#endif
}
static __device__ __forceinline__ float fexp2(float x) {
#if __has_builtin(__builtin_amdgcn_exp2f)
    return __builtin_amdgcn_exp2f(x);
#else
    return __expf(0.69314718056f * x);
#endif
}

// Raw barrier: drain LDS ops only (no vmcnt(0) drain -> prefetch loads stay in flight).
static __device__ __forceinline__ void bar_lds() {
    asm volatile("s_waitcnt lgkmcnt(0)" ::: "memory");
    __builtin_amdgcn_s_barrier();
}

// R10 step structure (116us, session best) at 8 items/block for REAL 4 waves/SIMD:
// grid 2048 x 128 threads = 4096 waves; VGPR=128 (R10-measured) => 4/SIMD fits.
// Each SIMD hosts 4 waves from 4 INDEPENDENT blocks (barrier couples only the
// 2-wave pair) -> 4 interleavable stall streams vs R10's 2 (per-wave busy ~22%).
// Lanes 8-15 mirror lanes 0-7 (i8); MFMA cols 8-15 discarded; LDS x/h rows 0-7
// only (writes predicated i16<8, mirror reads broadcast). woA staging dropped
// (W_out frags from global at tail) so LDS=12.5KB -> 8 blocks/CU fits 100KB.
// R3 retro-explained: its occupancy measured 18% not 38% -- 4/SIMD never tested.
__global__ __launch_bounds__(128, 2)
void dygkt12(const float* __restrict__ nodef, const float* __restrict__ edgef,
             const int* __restrict__ src_ids, const int* __restrict__ dst_ids,
             const float* __restrict__ times,
             const int* __restrict__ s_nids, const int* __restrict__ s_eids,
             const float* __restrict__ s_ts,
             const int* __restrict__ d_nids, const int* __restrict__ d_eids,
             const float* __restrict__ d_ts,
             const float* __restrict__ W_feat, const float* __restrict__ b_feat,
             const float* __restrict__ W_edge, const float* __restrict__ b_edge,
             const float* __restrict__ W_time, const float* __restrict__ b_time,
             const float* __restrict__ W_str,  const float* __restrict__ b_str,
             const float* __restrict__ W_out,  const float* __restrict__ b_out,
             const float* __restrict__ time_w, const float* __restrict__ time_b,
             const float* __restrict__ sWih, const float* __restrict__ sWhh,
             const float* __restrict__ sbih, const float* __restrict__ sbhh,
             const float* __restrict__ dWih, const float* __restrict__ dWhh,
             const float* __restrict__ dbih, const float* __restrict__ dbhh,
             float* __restrict__ out)
{
    __shared__ uint4 wfA[8][64];                        // W_feat^T A-frags, 8 KB
    __shared__ __align__(16) _Float16 xls[2][8 * 72];   // x^T slots (8 items)
    __shared__ __align__(16) _Float16 hls[2][8 * 72];   // h^T double buffer

    const int tid = threadIdx.x, w = tid >> 6, lane = tid & 63;
    const int g = lane >> 4, i16 = lane & 15, i8 = lane & 7;
    const bool is_src = (blockIdx.x & 1) == 0;
    const int b = (int)(blockIdx.x >> 1) * 8 + i8;      // this lane's item (mirrored)

    const float SRZ = -1.44269504089f;   // -log2e: sigmoid(x)=rcp(1+exp2(SRZ*x))
    const float SN  =  2.88539008178f;   // 2*log2e: tanh(x)=1-2*rcp(exp2(SN*x)+1)
    const floatx4 z4 = {0, 0, 0, 0};

    // ---- stage W_feat^T A-frags into LDS; zero hls[0] ----
    for (int q = tid; q < 512; q += 128) {
        int l = q & 63, tt = q >> 6;
        int kh = tt >> 2, mt = tt & 3, gg = l >> 4, ii = l & 15;
        float v[8];
        #pragma unroll
        for (int j = 0; j < 8; ++j)
            v[j] = W_feat[(32 * kh + 8 * gg + j) * 64 + 16 * mt + ii];
        wfA[tt][l] = make_uint4(pk2u(v[0],v[1]), pk2u(v[2],v[3]), pk2u(v[4],v[5]), pk2u(v[6],v[7]));
    }
    for (int q = tid; q < 8 * 72 / 2; q += 128) ((uint32_t*)hls[0])[q] = 0u;

    // ---- GRU weight A-frags for OUR row tiles (scaled; gate 0=r,1=z,2=n) ----
    const float* WI = is_src ? sWih : dWih;
    const float* WH = is_src ? sWhh : dWhh;
    uint4 wih[6][2], whh[6][2];   // [gate*2+tq][kh]
    #pragma unroll
    for (int gt = 0; gt < 3; ++gt) {
        const float s = (gt == 2) ? SN : SRZ;
        #pragma unroll
        for (int tq = 0; tq < 2; ++tq)
            #pragma unroll
            for (int kh = 0; kh < 2; ++kh) {
                int row = 64 * gt + 16 * (2 * w + tq) + i16;
                const float* p = WI + (size_t)row * 64 + 32 * kh + 8 * g;
                float4 a = *(const float4*)p, c = *(const float4*)(p + 4);
                wih[gt * 2 + tq][kh] = make_uint4(pk2u(s*a.x,s*a.y), pk2u(s*a.z,s*a.w),
                                                  pk2u(s*c.x,s*c.y), pk2u(s*c.z,s*c.w));
                const float* qq = WH + (size_t)row * 64 + 32 * kh + 8 * g;
                float4 e = *(const float4*)qq, f = *(const float4*)(qq + 4);
                whh[gt * 2 + tq][kh] = make_uint4(pk2u(s*e.x,s*e.y), pk2u(s*e.z,s*e.w),
                                                  pk2u(s*f.x,s*f.y), pk2u(s*f.z,s*f.w));
            }
    }

    // ---- time/edge/struct/bias bundle A-frags (unscaled: feeds x, not gates) ----
    uint4 wtA[2];
    #pragma unroll
    for (int tq = 0; tq < 2; ++tq) {
        int mt = 2 * w + tq;
        float v[8];
        #pragma unroll
        for (int j = 0; j < 8; ++j) {
            int k = 8 * g + j, dim = 16 * mt + i16;
            float x = 0.0f;
            if (k < 16)       x = W_time[k * 64 + dim];
            else if (k == 16) x = W_edge[dim];
            else if (k == 17) x = W_str[dim];
            else if (k == 18) x = b_edge[dim] + b_time[dim];
            else if (k == 19) x = is_src ? (b_feat[dim] + 2.0f * b_str[dim]) : b_str[dim];
            else if (k == 20) x = b_feat[dim];
            v[j] = x;
        }
        wtA[tq] = make_uint4(pk2u(v[0],v[1]), pk2u(v[2],v[3]), pk2u(v[4],v[5]), pk2u(v[6],v[7]));
    }

    // ---- gate bias C-init vectors (scaled) ----
    const float* BI = is_src ? sbih : dbih;
    const float* BH = is_src ? sbhh : dbhh;
    floatx4 brz[4], bin[2], bhn[2];   // brz: [0..1]=r, [2..3]=z
    #pragma unroll
    for (int gz = 0; gz < 2; ++gz)
        #pragma unroll
        for (int tq = 0; tq < 2; ++tq) {
            int r0 = 64 * gz + 16 * (2 * w + tq) + 4 * g;
            floatx4 v;
            #pragma unroll
            for (int r = 0; r < 4; ++r) v[r] = SRZ * (BI[r0 + r] + BH[r0 + r]);
            brz[gz * 2 + tq] = v;
        }
    #pragma unroll
    for (int tq = 0; tq < 2; ++tq) {
        int r0 = 128 + 16 * (2 * w + tq) + 4 * g;
        floatx4 vi, vh;
        #pragma unroll
        for (int r = 0; r < 4; ++r) { vi[r] = SN * BI[r0 + r]; vh[r] = SN * BH[r0 + r]; }
        bin[tq] = vi; bhn[tq] = vh;
    }

    // ---- per-lane (per-item) scalars (lanes 8-15 mirror via i8) ----
    const int* pn = (is_src ? s_nids : d_nids) + (size_t)b * NN;
    const int* pe = (is_src ? s_eids : d_eids) + (size_t)b * NN;
    const float* pt = (is_src ? s_ts : d_ts) + (size_t)b * NN;
    const float tqL = times[b];
    const int didL = dst_ids[b];
    const int oid = is_src ? didL : src_ids[b];
    const float dskill = is_src ? nodef[(size_t)didL * 64] : 0.0f;
    float twc[8], tbc[8];
    #pragma unroll
    for (int j = 0; j < 8; ++j) {
        int k = 8 * (g & 1) + j;
        twc[j] = time_w[k]; tbc[j] = time_b[k];
    }

    __syncthreads();   // wfA + hls[0] zeros visible (only block-wide sync)

    // ---- prime prefetch for t = 0 (incl. skill scalar -- no __shfl) ----
    int nidC = pn[0], eidC = pe[0];
    float tsC = pt[0];
    float e0C = edgef[4 * (size_t)eidC];
    float nskC = 0.0f;
    float4 nfa = {0,0,0,0}, nfb = {0,0,0,0}, nfc = {0,0,0,0}, nfd = {0,0,0,0};
    if (is_src) {
        const float* rp = nodef + (size_t)nidC * 64 + 8 * g;
        nfa = *(const float4*)rp;        nfb = *(const float4*)(rp + 4);
        nfc = *(const float4*)(rp + 32); nfd = *(const float4*)(rp + 36);
        nskC = nodef[(size_t)nidC * 64];
    }

    floatx4 hM[2] = {z4, z4};
    int cur = 0;

    for (int t = 0; t < NN; ++t) {
        // scalar prefetch for t+1
        int nidN = 0, eidN = 0; float tsN = 0.0f;
        if (t + 1 < NN) { nidN = pn[t + 1]; eidN = pe[t + 1]; tsN = pt[t + 1]; }

        // ---- B-frag: [tenc(16) | e0, sf, 1, 1, 0...] ----
        float sf = ((nidC == oid) ? 1.0f : 0.0f) +
                   ((is_src && nskC == dskill) ? 1.0f : 0.0f);
        float delta = tqL - tsC;
        uint4 tb4;
        if (g < 2) {
            float cv[8];
            #pragma unroll
            for (int j = 0; j < 8; ++j) cv[j] = __cosf(delta * twc[j] + tbc[j]);
            tb4 = make_uint4(pk2u(cv[0],cv[1]), pk2u(cv[2],cv[3]), pk2u(cv[4],cv[5]), pk2u(cv[6],cv[7]));
        } else if (g == 2) {
            tb4 = make_uint4(pk2u(e0C, sf), pk2u(1.0f, 1.0f), 0u, 0u);
        } else {
            tb4 = make_uint4(0u, 0u, 0u, 0u);
        }
        half8 tB = u2h(tb4);

        // ---- x rows for our tiles (cols 8-15 are discarded mirrors) ----
        if (is_src) {
            uint4 nf0 = make_uint4(pk2u(nfa.x,nfa.y), pk2u(nfa.z,nfa.w), pk2u(nfb.x,nfb.y), pk2u(nfb.z,nfb.w));
            uint4 nf1 = make_uint4(pk2u(nfc.x,nfc.y), pk2u(nfc.z,nfc.w), pk2u(nfd.x,nfd.y), pk2u(nfd.z,nfd.w));
            half8 nB0 = u2h(nf0), nB1 = u2h(nf1);
            #pragma unroll
            for (int tq = 0; tq < 2; ++tq) {
                int mt = 2 * w + tq;
                floatx4 a = MFMA(u2h(wfA[mt][lane]), nB0, z4);
                a = MFMA(u2h(wfA[4 + mt][lane]), nB1, a);
                floatx4 xacc = MFMA(u2h(wtA[tq]), tB, a);
                if (i16 < 8)
                    *(uint2*)&xls[cur][i16 * 72 + 32 * w + 16 * tq + 4 * g] =
                        make_uint2(pk2u(xacc[0], xacc[1]), pk2u(xacc[2], xacc[3]));
            }
        } else {
            #pragma unroll
            for (int tq = 0; tq < 2; ++tq) {
                floatx4 xacc = MFMA(u2h(wtA[tq]), tB, z4);
                if (i16 < 8)
                    *(uint2*)&xls[cur][i16 * 72 + 32 * w + 16 * tq + 4 * g] =
                        make_uint2(pk2u(xacc[0], xacc[1]), pk2u(xacc[2], xacc[3]));
            }
        }

        // ---- issue gathers for t+1 (incl. skill); in flight across the barrier ----
        float e0N = 0.0f, nskN = 0.0f;
        float4 na = {0,0,0,0}, nb = {0,0,0,0}, nc = {0,0,0,0}, nd = {0,0,0,0};
        if (t + 1 < NN) {
            e0N = edgef[4 * (size_t)eidN];
            if (is_src) {
                const float* rp = nodef + (size_t)nidN * 64 + 8 * g;
                na = *(const float4*)rp;        nb = *(const float4*)(rp + 4);
                nc = *(const float4*)(rp + 32); nd = *(const float4*)(rp + 36);
                nskN = nodef[(size_t)nidN * 64];
            }
        }

        bar_lds();

        // ---- full x and h B-frags (cols mirror via i8 -> LDS broadcast) ----
        half8 xB0 = u2h(*(const uint4*)&xls[cur][i8 * 72 + 8 * g]);
        half8 xB1 = u2h(*(const uint4*)&xls[cur][i8 * 72 + 32 + 8 * g]);
        half8 hB0 = u2h(*(const uint4*)&hls[cur][i8 * 72 + 8 * g]);
        half8 hB1 = u2h(*(const uint4*)&hls[cur][i8 * 72 + 32 + 8 * g]);

        // ---- gate GEMMs for our row tiles (24 MFMAs; scaled weights) ----
        floatx4 rg[2], zg[2], ia[2], ha[2];
        #pragma unroll
        for (int tq = 0; tq < 2; ++tq) {
            floatx4 a = MFMA(u2h(wih[tq][0]), xB0, brz[tq]);
            a = MFMA(u2h(wih[tq][1]), xB1, a);
            a = MFMA(u2h(whh[tq][0]), hB0, a);
            rg[tq] = MFMA(u2h(whh[tq][1]), hB1, a);
        }
        #pragma unroll
        for (int tq = 0; tq < 2; ++tq) {
            floatx4 a = MFMA(u2h(wih[2 + tq][0]), xB0, brz[2 + tq]);
            a = MFMA(u2h(wih[2 + tq][1]), xB1, a);
            a = MFMA(u2h(whh[2 + tq][0]), hB0, a);
            zg[tq] = MFMA(u2h(whh[2 + tq][1]), hB1, a);
        }
        #pragma unroll
        for (int tq = 0; tq < 2; ++tq) {
            floatx4 a = MFMA(u2h(wih[4 + tq][0]), xB0, bin[tq]);
            ia[tq] = MFMA(u2h(wih[4 + tq][1]), xB1, a);
            floatx4 c = MFMA(u2h(whh[4 + tq][0]), hB0, bhn[tq]);
            ha[tq] = MFMA(u2h(whh[4 + tq][1]), hB1, c);
        }

        // ---- gate math (scales pre-folded; mirror lanes compute harmless dups) ----
        #pragma unroll
        for (int tq = 0; tq < 2; ++tq)
            #pragma unroll
            for (int r = 0; r < 4; ++r) {
                float rr = frcp(1.0f + fexp2(rg[tq][r]));
                float zz = frcp(1.0f + fexp2(zg[tq][r]));
                float nn = 1.0f - 2.0f * frcp(fexp2(ia[tq][r] + rr * ha[tq][r]) + 1.0f);
                hM[tq][r] = nn + zz * (hM[tq][r] - nn);
            }

        // ---- write our h rows to the NEXT buffer (real cols only) ----
        if (i16 < 8) {
            #pragma unroll
            for (int tq = 0; tq < 2; ++tq)
                *(uint2*)&hls[cur ^ 1][i16 * 72 + 32 * w + 16 * tq + 4 * g] =
                    make_uint2(pk2u(hM[tq][0], hM[tq][1]), pk2u(hM[tq][2], hM[tq][3]));
        }

        cur ^= 1;
        nidC = nidN; eidC = eidN; tsC = tsN; e0C = e0N; nskC = nskN;
        nfa = na; nfb = nb; nfc = nc; nfd = nd;
    }

    // ---- tail: delta=0 time proj + edge(eid=0) proj [+ node_f(did)+b_feat for dst] ----
    float e00 = edgef[0];
    uint4 tt4;
    if (g < 2) {
        float cv[8];
        #pragma unroll
        for (int j = 0; j < 8; ++j) cv[j] = __cosf(tbc[j]);
        tt4 = make_uint4(pk2u(cv[0],cv[1]), pk2u(cv[2],cv[3]), pk2u(cv[4],cv[5]), pk2u(cv[6],cv[7]));
    } else if (g == 2) {
        tt4 = make_uint4(pk2u(e00, 0.0f), pk2u(1.0f, 0.0f), pk2u(is_src ? 0.0f : 1.0f, 0.0f), 0u);
    } else {
        tt4 = make_uint4(0u, 0u, 0u, 0u);
    }
    half8 tT = u2h(tt4);

    floatx4 tacc[2];
    #pragma unroll
    for (int tq = 0; tq < 2; ++tq) tacc[tq] = MFMA(u2h(wtA[tq]), tT, z4);
    if (!is_src) {
        const float* rp = nodef + (size_t)didL * 64 + 8 * g;
        float4 da = *(const float4*)rp,        db = *(const float4*)(rp + 4);
        float4 dc = *(const float4*)(rp + 32), dd = *(const float4*)(rp + 36);
        uint4 d0 = make_uint4(pk2u(da.x,da.y), pk2u(da.z,da.w), pk2u(db.x,db.y), pk2u(db.z,db.w));
        uint4 d1 = make_uint4(pk2u(dc.x,dc.y), pk2u(dc.z,dc.w), pk2u(dd.x,dd.y), pk2u(dd.z,dd.w));
        #pragma unroll
        for (int tq = 0; tq < 2; ++tq) {
            int mt = 2 * w + tq;
            tacc[tq] = MFMA(u2h(wfA[mt][lane]), u2h(d0), tacc[tq]);
            tacc[tq] = MFMA(u2h(wfA[4 + mt][lane]), u2h(d1), tacc[tq]);
        }
    }

    // ---- W_out^T A-frags for our tiles (global, L2-hot; tail-only) ----
    uint4 wo[2][2];
    #pragma unroll
    for (int tq = 0; tq < 2; ++tq)
        #pragma unroll
        for (int kh = 0; kh < 2; ++kh) {
            float v[8];
            #pragma unroll
            for (int j = 0; j < 8; ++j)
                v[j] = W_out[(32 * kh + 8 * g + j) * 64 + 16 * (2 * w + tq) + i16];
            wo[tq][kh] = make_uint4(pk2u(v[0],v[1]), pk2u(v[2],v[3]), pk2u(v[4],v[5]), pk2u(v[6],v[7]));
        }

    // ---- e = h + tail -> LDS; out = e @ W_out + b_out via MFMA ----
    if (i16 < 8) {
        #pragma unroll
        for (int tq = 0; tq < 2; ++tq) {
            floatx4 e = hM[tq] + tacc[tq];
            *(uint2*)&xls[0][i16 * 72 + 32 * w + 16 * tq + 4 * g] =
                make_uint2(pk2u(e[0], e[1]), pk2u(e[2], e[3]));
        }
    }
    bar_lds();
    half8 eB0 = u2h(*(const uint4*)&xls[0][i8 * 72 + 8 * g]);
    half8 eB1 = u2h(*(const uint4*)&xls[0][i8 * 72 + 32 + 8 * g]);

    const size_t obase = (is_src ? 0 : (size_t)BB * 64) + (size_t)b * 64;
    #pragma unroll
    for (int tq = 0; tq < 2; ++tq) {
        int mt = 2 * w + tq;
        floatx4 bo;
        #pragma unroll
        for (int r = 0; r < 4; ++r) bo[r] = b_out[16 * mt + 4 * g + r];
        floatx4 o = MFMA(u2h(wo[tq][0]), eB0, bo);
        o = MFMA(u2h(wo[tq][1]), eB1, o);
        if (i16 < 8) {
            #pragma unroll
            for (int r = 0; r < 4; ++r)
                out[obase + 16 * mt + 4 * g + r] = o[r];
        }
    }
}

extern "C" void kernel_launch(void* const* d_in, const int* in_sizes, int n_in,
                              void* d_out, int out_size, void* d_ws, size_t ws_size,
                              hipStream_t stream) {
    (void)in_sizes; (void)n_in; (void)d_ws; (void)ws_size; (void)out_size;
    const float* nodef  = (const float*)d_in[0];
    const float* edgef  = (const float*)d_in[1];
    const int*   srcid  = (const int*)  d_in[2];
    const int*   dstid  = (const int*)  d_in[3];
    const float* times  = (const float*)d_in[4];
    const int*   s_nids = (const int*)  d_in[5];
    const int*   s_eids = (const int*)  d_in[6];
    const float* s_ts   = (const float*)d_in[7];
    const int*   d_nids = (const int*)  d_in[8];
    const int*   d_eids = (const int*)  d_in[9];
    const float* d_ts   = (const float*)d_in[10];
    const float* W_feat = (const float*)d_in[11];
    const float* b_feat = (const float*)d_in[12];
    const float* W_edge = (const float*)d_in[13];
    const float* b_edge = (const float*)d_in[14];
    const float* W_time = (const float*)d_in[15];
    const float* b_time = (const float*)d_in[16];
    const float* W_str  = (const float*)d_in[17];
    const float* b_str  = (const float*)d_in[18];
    const float* W_out  = (const float*)d_in[19];
    const float* b_out  = (const float*)d_in[20];
    const float* time_w = (const float*)d_in[21];
    const float* time_b = (const float*)d_in[22];
    const float* sWih   = (const float*)d_in[23];
    const float* sWhh   = (const float*)d_in[24];
    const float* sbih   = (const float*)d_in[25];
    const float* sbhh   = (const float*)d_in[26];
    const float* dWih   = (const float*)d_in[27];
    const float* dWhh   = (const float*)d_in[28];
    const float* dbih   = (const float*)d_in[29];
    const float* dbhh   = (const float*)d_in[30];

    dim3 grid(2048), block(128);
    dygkt12<<<grid, block, 0, stream>>>(
        nodef, edgef, srcid, dstid, times,
        s_nids, s_eids, s_ts, d_nids, d_eids, d_ts,
        W_feat, b_feat, W_edge, b_edge, W_time, b_time,
        W_str, b_str, W_out, b_out, time_w, time_b,
        sWih, sWhh, sbih, sbhh, dWih, dWhh, dbih, dbhh,
        (float*)d_out);
}

// Round 12
// 240.925 us; speedup vs baseline: 1.6518x; 1.6518x over previous
//
#include <hip/hip_runtime.h>
#include <stdint.h>

#define BB 8192
#define NN 50

typedef _Float16 half8 __attribute__((ext_vector_type(8)));
typedef float floatx4 __attribute__((ext_vector_type(4)));

union FragU { uint4 u; half8 h; };
static __device__ __forceinline__ half8 u2h(uint4 u) { FragU f; f.u = u; return f.h; }

static __device__ __forceinline__ uint32_t pk2u(float a, float b) {
    auto p = __builtin_amdgcn_cvt_pkrtz(a, b);
    uint32_t u; __builtin_memcpy(&u, &p, 4); return u;
}

#define MFMA(A, B, C) __builtin_amdgcn_mfma_f32_16x16x32_f16((A), (B), (C), 0, 0, 0)

static __device__ __forceinline__ float frcp(float x) {
#if __has_builtin(__builtin_amdgcn_rcpf)
    return __builtin_amdgcn_rcpf(x);
#else
    return 1.0f / x;
#endif
}
static __device__ __forceinline__ float fexp2(float x) {
#if __has_builtin(__builtin_amdgcn_exp2f)
    return __builtin_amdgcn_exp2f(x);
#else
    return __expf(0.69314718056f * x);
#endif
}

// Raw barrier: drain LDS ops only (no vmcnt(0) drain -> prefetch loads stay in flight).
static __device__ __forceinline__ void bar_lds() {
    asm volatile("s_waitcnt lgkmcnt(0)" ::: "memory");
    __builtin_amdgcn_s_barrier();
}

// FINAL (session best, R10: 116us rocprof / 242us harness).
// 2-wave row-split GRU: block = 128 threads = 2 waves sharing 16 items; wave w
// owns rows [32w,32w+32). Full x and h exchanged through double-buffered LDS
// with ONE raw lgkm-only barrier per step (prefetch gathers stay in flight
// across it). Chain-shortening micro-fixes vs the original R1 structure:
//  (a) neighbor-skill scalar prefetched one step ahead (kills per-step ds_bpermute);
//  (c) sigmoid/tanh argument scales folded into Wih/Whh/biases.
// Explored+refuted alternatives (measured): 4-way row-split (172us, VALU dup),
// gi-precompute pipeline (135), producer/consumer waves (194, imbalance),
// barrier-free 8-item waves (614, spill), post-barrier B-build (141, extends
// serial phase), 8-item 2-split for 4 waves/SIMD (286, residency never rises
// above ~2/SIMD -- twice-measured). Residual is dependent-chain latency of the
// 50-step serial recurrence at 2 resident waves/SIMD; no pipe is saturated
// (VALU 40%, MFMA 16%, HBM 17%) and every overlap scheme loses more to
// duplication/imbalance/spill than it recovers.
__global__ __launch_bounds__(128, 2)
void dygkt11(const float* __restrict__ nodef, const float* __restrict__ edgef,
             const int* __restrict__ src_ids, const int* __restrict__ dst_ids,
             const float* __restrict__ times,
             const int* __restrict__ s_nids, const int* __restrict__ s_eids,
             const float* __restrict__ s_ts,
             const int* __restrict__ d_nids, const int* __restrict__ d_eids,
             const float* __restrict__ d_ts,
             const float* __restrict__ W_feat, const float* __restrict__ b_feat,
             const float* __restrict__ W_edge, const float* __restrict__ b_edge,
             const float* __restrict__ W_time, const float* __restrict__ b_time,
             const float* __restrict__ W_str,  const float* __restrict__ b_str,
             const float* __restrict__ W_out,  const float* __restrict__ b_out,
             const float* __restrict__ time_w, const float* __restrict__ time_b,
             const float* __restrict__ sWih, const float* __restrict__ sWhh,
             const float* __restrict__ sbih, const float* __restrict__ sbhh,
             const float* __restrict__ dWih, const float* __restrict__ dWhh,
             const float* __restrict__ dbih, const float* __restrict__ dbhh,
             float* __restrict__ out)
{
    __shared__ uint4 wfA[8][64];                        // W_feat^T A-frags, 8 KB
    __shared__ uint4 woA[8][64];                        // W_out^T  A-frags, 8 KB
    __shared__ __align__(16) _Float16 xls[2][16 * 72];  // double-buffered x^T
    __shared__ __align__(16) _Float16 hls[2][16 * 72];  // double-buffered h^T

    const int tid = threadIdx.x, w = tid >> 6, lane = tid & 63;
    const int g = lane >> 4, i16 = lane & 15;
    const bool is_src = blockIdx.x < 512;
    const int b = (int)(blockIdx.x & 511) * 16 + i16;   // this lane's item

    const float SRZ = -1.44269504089f;   // -log2e: sigmoid(x)=rcp(1+exp2(SRZ*x))
    const float SN  =  2.88539008178f;   // 2*log2e: tanh(x)=1-2*rcp(exp2(SN*x)+1)
    const floatx4 z4 = {0, 0, 0, 0};

    // ---- stage W_feat^T / W_out^T A-frags into LDS; zero hls[0] ----
    for (int q = tid; q < 512; q += 128) {
        int l = q & 63, tt = q >> 6;
        int kh = tt >> 2, mt = tt & 3, gg = l >> 4, ii = l & 15;
        float v[8], u[8];
        #pragma unroll
        for (int j = 0; j < 8; ++j) {
            int k = 32 * kh + 8 * gg + j, m = 16 * mt + ii;
            v[j] = W_feat[k * 64 + m];
            u[j] = W_out[k * 64 + m];
        }
        wfA[tt][l] = make_uint4(pk2u(v[0],v[1]), pk2u(v[2],v[3]), pk2u(v[4],v[5]), pk2u(v[6],v[7]));
        woA[tt][l] = make_uint4(pk2u(u[0],u[1]), pk2u(u[2],u[3]), pk2u(u[4],u[5]), pk2u(u[6],u[7]));
    }
    for (int q = tid; q < 16 * 72 / 2; q += 128) ((uint32_t*)hls[0])[q] = 0u;

    // ---- GRU weight A-frags for OUR row tiles (scaled; gate 0=r,1=z,2=n) ----
    const float* WI = is_src ? sWih : dWih;
    const float* WH = is_src ? sWhh : dWhh;
    uint4 wih[6][2], whh[6][2];   // [gate*2+tq][kh]
    #pragma unroll
    for (int gt = 0; gt < 3; ++gt) {
        const float s = (gt == 2) ? SN : SRZ;
        #pragma unroll
        for (int tq = 0; tq < 2; ++tq)
            #pragma unroll
            for (int kh = 0; kh < 2; ++kh) {
                int row = 64 * gt + 16 * (2 * w + tq) + i16;
                const float* p = WI + (size_t)row * 64 + 32 * kh + 8 * g;
                float4 a = *(const float4*)p, c = *(const float4*)(p + 4);
                wih[gt * 2 + tq][kh] = make_uint4(pk2u(s*a.x,s*a.y), pk2u(s*a.z,s*a.w),
                                                  pk2u(s*c.x,s*c.y), pk2u(s*c.z,s*c.w));
                const float* qq = WH + (size_t)row * 64 + 32 * kh + 8 * g;
                float4 e = *(const float4*)qq, f = *(const float4*)(qq + 4);
                whh[gt * 2 + tq][kh] = make_uint4(pk2u(s*e.x,s*e.y), pk2u(s*e.z,s*e.w),
                                                  pk2u(s*f.x,s*f.y), pk2u(s*f.z,s*f.w));
            }
    }

    // ---- time/edge/struct/bias bundle A-frags (unscaled: feeds x, not gates) ----
    uint4 wtA[2];
    #pragma unroll
    for (int tq = 0; tq < 2; ++tq) {
        int mt = 2 * w + tq;
        float v[8];
        #pragma unroll
        for (int j = 0; j < 8; ++j) {
            int k = 8 * g + j, dim = 16 * mt + i16;
            float x = 0.0f;
            if (k < 16)       x = W_time[k * 64 + dim];
            else if (k == 16) x = W_edge[dim];
            else if (k == 17) x = W_str[dim];
            else if (k == 18) x = b_edge[dim] + b_time[dim];
            else if (k == 19) x = is_src ? (b_feat[dim] + 2.0f * b_str[dim]) : b_str[dim];
            else if (k == 20) x = b_feat[dim];
            v[j] = x;
        }
        wtA[tq] = make_uint4(pk2u(v[0],v[1]), pk2u(v[2],v[3]), pk2u(v[4],v[5]), pk2u(v[6],v[7]));
    }

    // ---- gate bias C-init vectors (scaled) ----
    const float* BI = is_src ? sbih : dbih;
    const float* BH = is_src ? sbhh : dbhh;
    floatx4 brz[4], bin[2], bhn[2];   // brz: [0..1]=r, [2..3]=z
    #pragma unroll
    for (int gz = 0; gz < 2; ++gz)
        #pragma unroll
        for (int tq = 0; tq < 2; ++tq) {
            int r0 = 64 * gz + 16 * (2 * w + tq) + 4 * g;
            floatx4 v;
            #pragma unroll
            for (int r = 0; r < 4; ++r) v[r] = SRZ * (BI[r0 + r] + BH[r0 + r]);
            brz[gz * 2 + tq] = v;
        }
    #pragma unroll
    for (int tq = 0; tq < 2; ++tq) {
        int r0 = 128 + 16 * (2 * w + tq) + 4 * g;
        floatx4 vi, vh;
        #pragma unroll
        for (int r = 0; r < 4; ++r) { vi[r] = SN * BI[r0 + r]; vh[r] = SN * BH[r0 + r]; }
        bin[tq] = vi; bhn[tq] = vh;
    }

    // ---- per-lane (per-item) scalars ----
    const int* pn = (is_src ? s_nids : d_nids) + (size_t)b * NN;
    const int* pe = (is_src ? s_eids : d_eids) + (size_t)b * NN;
    const float* pt = (is_src ? s_ts : d_ts) + (size_t)b * NN;
    const float tqL = times[b];
    const int didL = dst_ids[b];
    const int oid = is_src ? didL : src_ids[b];
    const float dskill = is_src ? nodef[(size_t)didL * 64] : 0.0f;
    float twc[8], tbc[8];
    #pragma unroll
    for (int j = 0; j < 8; ++j) {
        int k = 8 * (g & 1) + j;
        twc[j] = time_w[k]; tbc[j] = time_b[k];
    }

    __syncthreads();   // wfA/woA + hls[0] zeros visible (only block-wide sync)

    // ---- prime prefetch for t = 0 (incl. skill scalar -- replaces __shfl) ----
    int nidC = pn[0], eidC = pe[0];
    float tsC = pt[0];
    float e0C = edgef[4 * (size_t)eidC];
    float nskC = 0.0f;
    float4 nfa = {0,0,0,0}, nfb = {0,0,0,0}, nfc = {0,0,0,0}, nfd = {0,0,0,0};
    if (is_src) {
        const float* rp = nodef + (size_t)nidC * 64 + 8 * g;
        nfa = *(const float4*)rp;        nfb = *(const float4*)(rp + 4);
        nfc = *(const float4*)(rp + 32); nfd = *(const float4*)(rp + 36);
        nskC = nodef[(size_t)nidC * 64];
    }

    floatx4 hM[2] = {z4, z4};
    int cur = 0;

    for (int t = 0; t < NN; ++t) {
        // scalar prefetch for t+1
        int nidN = 0, eidN = 0; float tsN = 0.0f;
        if (t + 1 < NN) { nidN = pn[t + 1]; eidN = pe[t + 1]; tsN = pt[t + 1]; }

        // ---- B-frag: [tenc(16) | e0, sf, 1, 1, 0...] (nskC: no __shfl) ----
        float sf = ((nidC == oid) ? 1.0f : 0.0f) +
                   ((is_src && nskC == dskill) ? 1.0f : 0.0f);
        float delta = tqL - tsC;
        uint4 tb4;
        if (g < 2) {
            float cv[8];
            #pragma unroll
            for (int j = 0; j < 8; ++j) cv[j] = __cosf(delta * twc[j] + tbc[j]);
            tb4 = make_uint4(pk2u(cv[0],cv[1]), pk2u(cv[2],cv[3]), pk2u(cv[4],cv[5]), pk2u(cv[6],cv[7]));
        } else if (g == 2) {
            tb4 = make_uint4(pk2u(e0C, sf), pk2u(1.0f, 1.0f), 0u, 0u);
        } else {
            tb4 = make_uint4(0u, 0u, 0u, 0u);
        }
        half8 tB = u2h(tb4);

        // ---- x rows for our tiles ----
        if (is_src) {
            uint4 nf0 = make_uint4(pk2u(nfa.x,nfa.y), pk2u(nfa.z,nfa.w), pk2u(nfb.x,nfb.y), pk2u(nfb.z,nfb.w));
            uint4 nf1 = make_uint4(pk2u(nfc.x,nfc.y), pk2u(nfc.z,nfc.w), pk2u(nfd.x,nfd.y), pk2u(nfd.z,nfd.w));
            half8 nB0 = u2h(nf0), nB1 = u2h(nf1);
            #pragma unroll
            for (int tq = 0; tq < 2; ++tq) {
                int mt = 2 * w + tq;
                floatx4 a = MFMA(u2h(wfA[mt][lane]), nB0, z4);
                a = MFMA(u2h(wfA[4 + mt][lane]), nB1, a);
                floatx4 xacc = MFMA(u2h(wtA[tq]), tB, a);
                *(uint2*)&xls[cur][i16 * 72 + 32 * w + 16 * tq + 4 * g] =
                    make_uint2(pk2u(xacc[0], xacc[1]), pk2u(xacc[2], xacc[3]));
            }
        } else {
            #pragma unroll
            for (int tq = 0; tq < 2; ++tq) {
                floatx4 xacc = MFMA(u2h(wtA[tq]), tB, z4);
                *(uint2*)&xls[cur][i16 * 72 + 32 * w + 16 * tq + 4 * g] =
                    make_uint2(pk2u(xacc[0], xacc[1]), pk2u(xacc[2], xacc[3]));
            }
        }

        // ---- issue gathers for t+1 (incl. skill); in flight across the barrier ----
        float e0N = 0.0f, nskN = 0.0f;
        float4 na = {0,0,0,0}, nb = {0,0,0,0}, nc = {0,0,0,0}, nd = {0,0,0,0};
        if (t + 1 < NN) {
            e0N = edgef[4 * (size_t)eidN];
            if (is_src) {
                const float* rp = nodef + (size_t)nidN * 64 + 8 * g;
                na = *(const float4*)rp;        nb = *(const float4*)(rp + 4);
                nc = *(const float4*)(rp + 32); nd = *(const float4*)(rp + 36);
                nskN = nodef[(size_t)nidN * 64];
            }
        }

        bar_lds();

        // ---- full x and h B-frags (rows 0..63, both waves' halves) ----
        half8 xB0 = u2h(*(const uint4*)&xls[cur][i16 * 72 + 8 * g]);
        half8 xB1 = u2h(*(const uint4*)&xls[cur][i16 * 72 + 32 + 8 * g]);
        half8 hB0 = u2h(*(const uint4*)&hls[cur][i16 * 72 + 8 * g]);
        half8 hB1 = u2h(*(const uint4*)&hls[cur][i16 * 72 + 32 + 8 * g]);

        // ---- gate GEMMs for our row tiles (24 MFMAs; scaled weights) ----
        floatx4 rg[2], zg[2], ia[2], ha[2];
        #pragma unroll
        for (int tq = 0; tq < 2; ++tq) {
            floatx4 a = MFMA(u2h(wih[tq][0]), xB0, brz[tq]);
            a = MFMA(u2h(wih[tq][1]), xB1, a);
            a = MFMA(u2h(whh[tq][0]), hB0, a);
            rg[tq] = MFMA(u2h(whh[tq][1]), hB1, a);
        }
        #pragma unroll
        for (int tq = 0; tq < 2; ++tq) {
            floatx4 a = MFMA(u2h(wih[2 + tq][0]), xB0, brz[2 + tq]);
            a = MFMA(u2h(wih[2 + tq][1]), xB1, a);
            a = MFMA(u2h(whh[2 + tq][0]), hB0, a);
            zg[tq] = MFMA(u2h(whh[2 + tq][1]), hB1, a);
        }
        #pragma unroll
        for (int tq = 0; tq < 2; ++tq) {
            floatx4 a = MFMA(u2h(wih[4 + tq][0]), xB0, bin[tq]);
            ia[tq] = MFMA(u2h(wih[4 + tq][1]), xB1, a);
            floatx4 c = MFMA(u2h(whh[4 + tq][0]), hB0, bhn[tq]);
            ha[tq] = MFMA(u2h(whh[4 + tq][1]), hB1, c);
        }

        // ---- gate math (scales pre-folded into weights/biases) ----
        #pragma unroll
        for (int tq = 0; tq < 2; ++tq)
            #pragma unroll
            for (int r = 0; r < 4; ++r) {
                float rr = frcp(1.0f + fexp2(rg[tq][r]));
                float zz = frcp(1.0f + fexp2(zg[tq][r]));
                float nn = 1.0f - 2.0f * frcp(fexp2(ia[tq][r] + rr * ha[tq][r]) + 1.0f);
                hM[tq][r] = nn + zz * (hM[tq][r] - nn);
            }

        // ---- write our h rows to the NEXT buffer ----
        #pragma unroll
        for (int tq = 0; tq < 2; ++tq)
            *(uint2*)&hls[cur ^ 1][i16 * 72 + 32 * w + 16 * tq + 4 * g] =
                make_uint2(pk2u(hM[tq][0], hM[tq][1]), pk2u(hM[tq][2], hM[tq][3]));

        cur ^= 1;
        nidC = nidN; eidC = eidN; tsC = tsN; e0C = e0N; nskC = nskN;
        nfa = na; nfb = nb; nfc = nc; nfd = nd;
    }

    // ---- tail: delta=0 time proj + edge(eid=0) proj [+ node_f(did)+b_feat for dst] ----
    float e00 = edgef[0];
    uint4 tt4;
    if (g < 2) {
        float cv[8];
        #pragma unroll
        for (int j = 0; j < 8; ++j) cv[j] = __cosf(tbc[j]);
        tt4 = make_uint4(pk2u(cv[0],cv[1]), pk2u(cv[2],cv[3]), pk2u(cv[4],cv[5]), pk2u(cv[6],cv[7]));
    } else if (g == 2) {
        tt4 = make_uint4(pk2u(e00, 0.0f), pk2u(1.0f, 0.0f), pk2u(is_src ? 0.0f : 1.0f, 0.0f), 0u);
    } else {
        tt4 = make_uint4(0u, 0u, 0u, 0u);
    }
    half8 tT = u2h(tt4);

    floatx4 tacc[2];
    #pragma unroll
    for (int tq = 0; tq < 2; ++tq) tacc[tq] = MFMA(u2h(wtA[tq]), tT, z4);
    if (!is_src) {
        const float* rp = nodef + (size_t)didL * 64 + 8 * g;
        float4 da = *(const float4*)rp,        db = *(const float4*)(rp + 4);
        float4 dc = *(const float4*)(rp + 32), dd = *(const float4*)(rp + 36);
        uint4 d0 = make_uint4(pk2u(da.x,da.y), pk2u(da.z,da.w), pk2u(db.x,db.y), pk2u(db.z,db.w));
        uint4 d1 = make_uint4(pk2u(dc.x,dc.y), pk2u(dc.z,dc.w), pk2u(dd.x,dd.y), pk2u(dd.z,dd.w));
        #pragma unroll
        for (int tq = 0; tq < 2; ++tq) {
            int mt = 2 * w + tq;
            tacc[tq] = MFMA(u2h(wfA[mt][lane]), u2h(d0), tacc[tq]);
            tacc[tq] = MFMA(u2h(wfA[4 + mt][lane]), u2h(d1), tacc[tq]);
        }
    }

    // ---- e = h + tail -> LDS; out = e @ W_out + b_out via MFMA ----
    #pragma unroll
    for (int tq = 0; tq < 2; ++tq) {
        floatx4 e = hM[tq] + tacc[tq];
        *(uint2*)&xls[0][i16 * 72 + 32 * w + 16 * tq + 4 * g] =
            make_uint2(pk2u(e[0], e[1]), pk2u(e[2], e[3]));
    }
    bar_lds();
    half8 eB0 = u2h(*(const uint4*)&xls[0][i16 * 72 + 8 * g]);
    half8 eB1 = u2h(*(const uint4*)&xls[0][i16 * 72 + 32 + 8 * g]);

    const size_t obase = (is_src ? 0 : (size_t)BB * 64) + (size_t)b * 64;
    #pragma unroll
    for (int tq = 0; tq < 2; ++tq) {
        int mt = 2 * w + tq;
        floatx4 bo;
        #pragma unroll
        for (int r = 0; r < 4; ++r) bo[r] = b_out[16 * mt + 4 * g + r];
        floatx4 o = MFMA(u2h(woA[mt][lane]), eB0, bo);
        o = MFMA(u2h(woA[4 + mt][lane]), eB1, o);
        #pragma unroll
        for (int r = 0; r < 4; ++r)
            out[obase + 16 * mt + 4 * g + r] = o[r];
    }
}

extern "C" void kernel_launch(void* const* d_in, const int* in_sizes, int n_in,
                              void* d_out, int out_size, void* d_ws, size_t ws_size,
                              hipStream_t stream) {
    (void)in_sizes; (void)n_in; (void)d_ws; (void)ws_size; (void)out_size;
    const float* nodef  = (const float*)d_in[0];
    const float* edgef  = (const float*)d_in[1];
    const int*   srcid  = (const int*)  d_in[2];
    const int*   dstid  = (const int*)  d_in[3];
    const float* times  = (const float*)d_in[4];
    const int*   s_nids = (const int*)  d_in[5];
    const int*   s_eids = (const int*)  d_in[6];
    const float* s_ts   = (const float*)d_in[7];
    const int*   d_nids = (const int*)  d_in[8];
    const int*   d_eids = (const int*)  d_in[9];
    const float* d_ts   = (const float*)d_in[10];
    const float* W_feat = (const float*)d_in[11];
    const float* b_feat = (const float*)d_in[12];
    const float* W_edge = (const float*)d_in[13];
    const float* b_edge = (const float*)d_in[14];
    const float* W_time = (const float*)d_in[15];
    const float* b_time = (const float*)d_in[16];
    const float* W_str  = (const float*)d_in[17];
    const float* b_str  = (const float*)d_in[18];
    const float* W_out  = (const float*)d_in[19];
    const float* b_out  = (const float*)d_in[20];
    const float* time_w = (const float*)d_in[21];
    const float* time_b = (const float*)d_in[22];
    const float* sWih   = (const float*)d_in[23];
    const float* sWhh   = (const float*)d_in[24];
    const float* sbih   = (const float*)d_in[25];
    const float* sbhh   = (const float*)d_in[26];
    const float* dWih   = (const float*)d_in[27];
    const float* dWhh   = (const float*)d_in[28];
    const float* dbih   = (const float*)d_in[29];
    const float* dbhh   = (const float*)d_in[30];

    dim3 grid(1024), block(128);
    dygkt11<<<grid, block, 0, stream>>>(
        nodef, edgef, srcid, dstid, times,
        s_nids, s_eids, s_ts, d_nids, d_eids, d_ts,
        W_feat, b_feat, W_edge, b_edge, W_time, b_time,
        W_str, b_str, W_out, b_out, time_w, time_b,
        sWih, sWhh, sbih, sbhh, dWih, dWhh, dbih, dbhh,
        (float*)d_out);
}